// Round 3
// baseline (179.228 us; speedup 1.0000x reference)
//
#include <hip/hip_runtime.h>

// Embedding gather: out[t, :] = weight[ids[t], :]
// B*S = 8192 tokens, D = 1024 fp32 per row (4 KiB).
//
// Structure (round 1, kept): one wave per token row, 2 tokens/wave,
// 8 outstanding 16B loads per lane. Round-1 A/B showed this is NOT
// latency-bound (8x MLP was neutral), so this round targets stream
// efficiency instead:
//   - output stores are NONTEMPORAL (global_store ... nt): out is never
//     re-read and gets poison-filled by the harness anyway, so letting it
//     allocate in L2 only evicts weight rows (dup-row reuse) and adds
//     writeback pressure against the gather read stream.
// Round-2 fix: __builtin_nontemporal_store needs a clang vector type,
// not HIP's float4 class — use ext_vector_type(4) float (same layout,
// same global_store_dwordx4, plus nt flag).

#define D_DIM 1024

typedef float floatx4 __attribute__((ext_vector_type(4)));

__global__ __launch_bounds__(256) void embed_gather_kernel(
    const int* __restrict__ ids,
    const float* __restrict__ weight,
    float* __restrict__ out,
    int n_tokens)
{
    const int lane = (int)(threadIdx.x & 63u);   // lane within wave
    const int wave = (int)(threadIdx.x >> 6);    // 0..3
    const int nwaves = (int)gridDim.x * 4;       // total waves in grid
    const int t0 = (int)blockIdx.x * 4 + wave;   // first token for this wave
    const int t1 = t0 + nwaves;                  // second token (second half)

    if (t0 >= n_tokens) return;
    const bool has1 = (t1 < n_tokens);

    // Wave-uniform id loads (issued together, up front).
    const int row0 = ids[t0];
    const int row1 = has1 ? ids[t1] : row0;  // alias row0 so loads stay unconditional

    const floatx4* __restrict__ s0 =
        reinterpret_cast<const floatx4*>(weight + (size_t)row0 * D_DIM) + lane;
    const floatx4* __restrict__ s1 =
        reinterpret_cast<const floatx4*>(weight + (size_t)row1 * D_DIM) + lane;
    floatx4* __restrict__ d0 =
        reinterpret_cast<floatx4*>(out + (size_t)t0 * D_DIM) + lane;
    floatx4* __restrict__ d1 =
        reinterpret_cast<floatx4*>(out + (size_t)t1 * D_DIM) + lane;

    // 8 independent 16B loads in flight before any store needs a waitcnt.
    floatx4 a0 = s0[0], a1 = s0[64], a2 = s0[128], a3 = s0[192];
    floatx4 b0 = s1[0], b1 = s1[64], b2 = s1[128], b3 = s1[192];

    // Nontemporal stores: don't allocate output lines in L2.
    __builtin_nontemporal_store(a0, d0);
    __builtin_nontemporal_store(a1, d0 + 64);
    __builtin_nontemporal_store(a2, d0 + 128);
    __builtin_nontemporal_store(a3, d0 + 192);
    if (has1) {
        __builtin_nontemporal_store(b0, d1);
        __builtin_nontemporal_store(b1, d1 + 64);
        __builtin_nontemporal_store(b2, d1 + 128);
        __builtin_nontemporal_store(b3, d1 + 192);
    }
}

extern "C" void kernel_launch(void* const* d_in, const int* in_sizes, int n_in,
                              void* d_out, int out_size, void* d_ws, size_t ws_size,
                              hipStream_t stream) {
    const int*   ids    = (const int*)d_in[0];     // token_ids [B,S] int32
    const float* weight = (const float*)d_in[1];   // [VOCAB, D] fp32
    float*       out    = (float*)d_out;           // [B,S,D] fp32

    const int n_tokens = in_sizes[0];              // B*S = 8192

    // 4 waves/block * 2 tokens/wave = 8 tokens per block.
    const int blocks = (n_tokens + 7) / 8;         // 1024 for 8192 tokens
    embed_gather_kernel<<<blocks, 256, 0, stream>>>(ids, weight, out, n_tokens);
}